// Round 2
// baseline (195.506 us; speedup 1.0000x reference)
//
#include <hip/hip_runtime.h>
#include <hip/hip_bf16.h>
#include <stdint.h>

typedef __attribute__((ext_vector_type(8))) short short8;
typedef __attribute__((ext_vector_type(4))) float f32x4;
typedef __attribute__((ext_vector_type(4))) unsigned int u32x4;
typedef __attribute__((ext_vector_type(2))) unsigned int u32x2;

// Skeleton (fixed in reference)
__constant__ __align__(16) int NBRC[17][4] = {
    {7, 1, 4, 0}, {0, 2, 0, 0}, {1, 3, 0, 0}, {2, 0, 0, 0},
    {0, 5, 0, 0}, {4, 6, 0, 0}, {5, 0, 0, 0}, {0, 8, 0, 0},
    {7, 9, 11, 14}, {8, 10, 0, 0}, {9, 0, 0, 0}, {8, 12, 0, 0},
    {11, 13, 0, 0}, {12, 0, 0, 0}, {8, 15, 0, 0}, {14, 16, 0, 0},
    {15, 0, 0, 0}};
__constant__ int DEGC[17] = {3,2,2,1,2,2,1,2,4,2,1,2,2,1,2,2,1};
__constant__ float RDEGC[5] = {0.f, 1.f, 0.5f, 0.33333334f, 0.25f};
// per-wave output-joint-tile assignment, balanced so sum(deg) = 8 per wave
__constant__ int WNT[4] = {3, 4, 5, 5};
__constant__ int WJT[4][5] = {{8, 1, 2, 0, 0},
                              {0, 4, 5, 3, 0},
                              {7, 9, 11, 6, 10},
                              {12, 14, 15, 13, 16}};

__device__ inline unsigned short f2bf(float f) {
  union { float f; uint32_t u; } v; v.f = f;
  uint32_t u = v.u;
  uint32_t r = u + 0x7fffu + ((u >> 16) & 1u);  // RNE
  return (unsigned short)(r >> 16);
}
// hardware v_cvt_pk_bf16_f32 (RNE), a in low 16, b in high 16
__device__ inline uint32_t pk2(float a, float b) {
  union { __hip_bfloat162 h; uint32_t u; } v;
  v.h = __float22bfloat162_rn(make_float2(a, b));
  return v.u;
}
__device__ inline f32x4 mfma16(short8 a, short8 b, f32x4 c) {
  return __builtin_amdgcn_mfma_f32_16x16x32_bf16(a, b, c, 0, 0, 0);
}

// ---------------- prep kernel (unchanged) ----------------
__global__ void prep(const float* __restrict__ W1,
                     const float* __restrict__ W2,
                     const float* __restrict__ Wp2,
                     const float* __restrict__ W3,
                     const float* __restrict__ Wp1,
                     const float* __restrict__ b3,
                     const float* __restrict__ bp1,
                     short* __restrict__ W1b,
                     short* __restrict__ W2b,
                     short* __restrict__ Wp2b,
                     short* __restrict__ Mb,
                     float* __restrict__ bp1p) {
  __shared__ float w3s[4096];
  __shared__ float Qs[256];
  const int tid = threadIdx.x;
  const int bx = blockIdx.x;
  if (bx < 272) {
    for (int q = tid; q < 4096; q += 256) w3s[q] = W3[q];
    {
      int ro = tid >> 6, k = tid & 63;
      int r = bx * 4 + ro;
      int f = r / 17, i = r - f * 17;
      int dj = DEGC[i];
      float s = 0.f;
#pragma unroll
      for (int t = 0; t < 4; t++) {
        if (t < dj) {
          int nb = NBRC[i][t];
          s += RDEGC[DEGC[nb]] * Wp1[f * 1088 + nb * 64 + k];
        }
      }
      Qs[ro * 64 + k] = s;
    }
    __syncthreads();
    {
      int ro = tid >> 6, c = tid & 63;
      int r = bx * 4 + ro;
      int f = r / 17, i = r - f * 17;
      float s = 0.f;
#pragma unroll
      for (int k = 0; k < 64; k++) s += Qs[ro * 64 + k] * w3s[k * 64 + c];
      int col = i * 64 + c;
      int kk = col >> 5, qq = (col >> 3) & 3, cb = col & 7;
      int w = f >> 4, l15 = f & 15;
      Mb[(((w * 34 + kk) * 64) + qq * 16 + l15) * 8 + cb] = (short)f2bf(s);
    }
  } else if (bx < 354) {
    int q = (bx - 272) * 256 + tid;
    if (q < 4096) W2b[q] = (short)f2bf(W2[q]);
    int q2 = q - 4096;
    if (q2 >= 0 && q2 < 16384) Wp2b[q2] = (short)f2bf(Wp2[q2]);
    int q3 = q - 20480;
    if (q3 >= 0 && q3 < 512) {
      int k = q3 & 7;
      W1b[q3] = (k < 3) ? (short)f2bf(W1[(q3 >> 3) * 3 + k]) : (short)0;
    }
  } else {
    int wv = tid >> 6, l = tid & 63;
    int f = (bx - 354) * 4 + wv;
    float s = 0.f;
#pragma unroll
    for (int i = 0; i < 17; i++) s += Wp1[f * 1088 + i * 64 + l] * b3[l];
#pragma unroll
    for (int off = 32; off > 0; off >>= 1) s += __shfl_down(s, off);
    if (l == 0) bp1p[f] = bp1[f] + s;
  }
}

// ---------------- main fused kernel ----------------
// 32 elements/block, 512 threads = 8 waves in two 16-element groups
// (waves 0-3 = group 0, 4-7 = group 1). Per-element barrier cost and
// per-block weight re-reads (Mb/Wp2b/W2b through L2) are halved vs the
// 16-elem version. agg0 is fused into Layer 1 (quad-0 lanes compute the
// 3-feature neighbor sums from xs directly) -> one fewer phase+barrier.
// hbuf stride-64 bf16, XOR-swizzled (byte ^= (row&7)<<4). zb overlays xs.
// LDS = 69632 + 6528 + 768 = 76928 B -> 2 blocks/CU, 16 waves/CU.
__launch_bounds__(512, 4)
__global__ void gcn_main(const float* __restrict__ X,
                         const short* __restrict__ Mb,
                         const short* __restrict__ Wp2b,
                         const short* __restrict__ W2b,
                         const short* __restrict__ W1b,
                         const float* __restrict__ bp1p,
                         const float* __restrict__ b1g,
                         const float* __restrict__ b2g,
                         const float* __restrict__ bp2g,
                         float* __restrict__ OUT) {
  __shared__ __align__(16) short hbuf[2 * 272 * 64];  // 69632 B
  __shared__ __align__(16) float xs[2 * 816];         // 6528 B; zb overlays late
  __shared__ __align__(16) float sbias[192];          // 768 B: b1|b2|bp1p

  const int tid = threadIdx.x;
  const int wave = tid >> 6;
  const int g = wave >> 2;     // element group 0/1
  const int wg = wave & 3;     // wave-in-group
  const int lane = tid & 63;
  const int ln15 = lane & 15;
  const int quad = lane >> 4;
  const int e0 = blockIdx.x * 32 + g * 16;

  char* hb = (char*)hbuf + g * 34816;
  float* xsg = xs + g * 816;
  auto hswz = [](int row, int cb) { return row * 128 + (cb ^ ((row & 7) << 4)); };

  // ---- init ----
  if (tid < 408) ((f32x4*)xs)[tid] = ((const f32x4*)(X + (size_t)blockIdx.x * 32 * 51))[tid];
  short8 w1f[4];
#pragma unroll
  for (int ft = 0; ft < 4; ft++)
    w1f[ft] = *(const short8*)(W1b + (ft * 16 + ln15) * 8);
  if (tid < 192) {
    float v;
    if (tid < 64) v = b1g[tid];
    else if (tid < 128) v = b2g[tid - 64];
    else v = bp1p[tid - 128];
    sbias[tid] = v;
  }
  __syncthreads();  // xs, sbias ready

  auto wb = [&](f32x4 c, int j, int ft, int bofs, float scale) {
    int r = j * 16 + ln15;
    int fb = ft * 16 + quad * 4;
    f32x4 bv = *(const f32x4*)&sbias[bofs + fb];
    float v0 = fmaxf(c.x * scale + bv.x, 0.f);
    float v1 = fmaxf(c.y * scale + bv.y, 0.f);
    float v2 = fmaxf(c.z * scale + bv.z, 0.f);
    float v3 = fmaxf(c.w * scale + bv.w, 0.f);
    u32x2 pk;
    pk.x = pk2(v0, v1);
    pk.y = pk2(v2, v3);
    *(u32x2*)(hb + hswz(r, fb * 2)) = pk;
  };

  const int nt = WNT[wg];

  // ---- Layer 1 with fused agg0 (quad-0 lanes build the B fragment) ----
#pragma unroll
  for (int t = 0; t < 5; t++) {
    if (t < nt) {
      int j = WJT[wg][t];
      union { short8 s; u32x4 u; } fr;
      fr.u = (u32x4){0u, 0u, 0u, 0u};
      if (quad == 0) {
        int4 nb = *(const int4*)(&NBRC[j][0]);
        int dj = DEGC[j];
        float s0, s1, s2;
        {
          int b = ln15 * 51 + nb.x * 3;
          s0 = xsg[b]; s1 = xsg[b + 1]; s2 = xsg[b + 2];
        }
        if (dj > 1) {
          int b = ln15 * 51 + nb.y * 3;
          s0 += xsg[b]; s1 += xsg[b + 1]; s2 += xsg[b + 2];
        }
        if (dj > 2) {
          int b = ln15 * 51 + nb.z * 3;
          s0 += xsg[b]; s1 += xsg[b + 1]; s2 += xsg[b + 2];
        }
        if (dj > 3) {
          int b = ln15 * 51 + nb.w * 3;
          s0 += xsg[b]; s1 += xsg[b + 1]; s2 += xsg[b + 2];
        }
        float w = RDEGC[dj];
        fr.u.x = pk2(s0 * w, s1 * w);
        fr.u.y = pk2(s2 * w, 0.f);
      }
      f32x4 a[4];
#pragma unroll
      for (int ft = 0; ft < 4; ft++) {
        f32x4 z = (f32x4){0.f, 0.f, 0.f, 0.f};
        a[ft] = mfma16(w1f[ft], fr.s, z);
      }
#pragma unroll
      for (int ft = 0; ft < 4; ft++) wb(a[ft], j, ft, 0, 1.f);
    }
  }
  __syncthreads();  // h1 ready

  const short8* mrow = ((const short8*)Mb) + (size_t)wg * 34 * 64 + lane;
  short8 pf[8];

  // ---- Layer 2: block-sparse MFMA aggregation, kk-outer ----
  {
    f32x4 acc[5][4];
#pragma unroll
    for (int t = 0; t < 5; t++)
      if (t < nt)
#pragma unroll
        for (int ft = 0; ft < 4; ft++) acc[t][ft] = (f32x4){0.f, 0.f, 0.f, 0.f};
#pragma unroll
    for (int kk = 0; kk < 2; kk++) {
      short8 w2f[4];
#pragma unroll
      for (int ft = 0; ft < 4; ft++)
        w2f[ft] = *(const short8*)(W2b + (ft * 16 + ln15) * 64 + kk * 32 + quad * 8);
#pragma unroll
      for (int t = 0; t < 5; t++) {
        if (t < nt) {
          int j = WJT[wg][t];
          int dj = DEGC[j];
#pragma unroll
          for (int s = 0; s < 4; s++) {
            if (s < dj) {
              int i = NBRC[j][s];
              short8 bf = *(const short8*)(hb + hswz(i * 16 + ln15, kk * 64 + quad * 16));
#pragma unroll
              for (int ft = 0; ft < 4; ft++)
                acc[t][ft] = mfma16(w2f[ft], bf, acc[t][ft]);
            }
          }
        }
      }
    }
    __syncthreads();  // all h1 reads done before overwrite
#pragma unroll
    for (int t = 0; t < 5; t++)
      if (t < nt) {
        int j = WJT[wg][t];
        float w = RDEGC[DEGC[j]];
#pragma unroll
        for (int ft = 0; ft < 4; ft++) wb(acc[t][ft], j, ft, 64, w);
      }
    // issue pool prefetch before the barrier: L2 latency hides behind sync
#pragma unroll
    for (int p = 0; p < 8; p++) pf[p] = mrow[p * 64];
  }
  __syncthreads();  // h2 ready

  // ---- Pool (folded layer3+pool1), Mb swizzled + software-pipelined ----
  f32x4 zc;
  {
    f32x4 accA = (f32x4){0.f, 0.f, 0.f, 0.f};
    f32x4 accB = (f32x4){0.f, 0.f, 0.f, 0.f};
#pragma unroll
    for (int kk = 0; kk < 34; kk++) {
      short8 af = pf[kk & 7];
      if (kk + 8 < 34) pf[kk & 7] = mrow[(kk + 8) * 64];
      int i = kk >> 1;
      short8 bf = *(const short8*)(hb + hswz(i * 16 + ln15, (kk & 1) * 64 + quad * 16));
      if (kk & 1) accB = mfma16(af, bf, accB);
      else accA = mfma16(af, bf, accA);
    }
    zc = accA + accB;
  }
  // prefetch Wp2 fragments; latency hides behind zb pack + barrier
  short8 wp2f[4][2];
#pragma unroll
  for (int t = 0; t < 4; t++) {
    int ot = wg + 4 * t;
    wp2f[t][0] = *(const short8*)(Wp2b + (ot * 16 + ln15) * 64 + quad * 8);
    wp2f[t][1] = *(const short8*)(Wp2b + (ot * 16 + ln15) * 64 + 32 + quad * 8);
  }
  char* zbB = (char*)xsg;  // overlay: xs dead since L1 (3 barriers ago)
  {
    int fb = wg * 16 + quad * 4;
    f32x4 bv = *(const f32x4*)&sbias[128 + fb];
    float v0 = fmaxf(zc.x + bv.x, 0.f);
    float v1 = fmaxf(zc.y + bv.y, 0.f);
    float v2 = fmaxf(zc.z + bv.z, 0.f);
    float v3 = fmaxf(zc.w + bv.w, 0.f);
    u32x2 pk;
    pk.x = pk2(v0, v1);
    pk.y = pk2(v2, v3);
    *(u32x2*)(zbB + hswz(ln15, fb * 2)) = pk;
  }
  __syncthreads();  // zb ready

  // ---- Pool layer 2: out = Wp2 * z + bp2 ----
  {
    short8 bf0 = *(const short8*)(zbB + hswz(ln15, quad * 16));
    short8 bf1 = *(const short8*)(zbB + hswz(ln15, 64 + quad * 16));
#pragma unroll
    for (int t = 0; t < 4; t++) {
      int ot = wg + 4 * t;
      f32x4 a = (f32x4){0.f, 0.f, 0.f, 0.f};
      a = mfma16(wp2f[t][0], bf0, a);
      a = mfma16(wp2f[t][1], bf1, a);
      int ob = ot * 16 + quad * 4;
      f32x4 bv = *(const f32x4*)&bp2g[ob];
      f32x4 res = a + bv;
      *(f32x4*)(OUT + (size_t)(e0 + ln15) * 256 + ob) = res;
    }
  }
}

extern "C" void kernel_launch(void* const* d_in, const int* in_sizes, int n_in,
                              void* d_out, int out_size, void* d_ws, size_t ws_size,
                              hipStream_t stream) {
  const float* X = (const float*)d_in[0];
  const float* W1 = (const float*)d_in[2];
  const float* b1 = (const float*)d_in[3];
  const float* W2 = (const float*)d_in[4];
  const float* b2 = (const float*)d_in[5];
  const float* W3 = (const float*)d_in[6];
  const float* b3 = (const float*)d_in[7];
  const float* Wp1 = (const float*)d_in[8];
  const float* bp1 = (const float*)d_in[9];
  const float* Wp2 = (const float*)d_in[10];
  const float* bp2 = (const float*)d_in[11];
  float* OUT = (float*)d_out;
  const int B = in_sizes[0] / 51;

  char* ws = (char*)d_ws;
  short* Mb = (short*)(ws + 0);          // 64*1088*2 = 139264 (swizzled)
  short* Wp2b = (short*)(ws + 139264);   // 32768
  short* W2b = (short*)(ws + 172032);    // 8192
  short* W1b = (short*)(ws + 180224);    // 1024
  float* bp1p = (float*)(ws + 181248);   // 256

  prep<<<370, 256, 0, stream>>>(W1, W2, Wp2, W3, Wp1, b3, bp1,
                                W1b, W2b, Wp2b, Mb, bp1p);
  gcn_main<<<B / 32, 512, 0, stream>>>(X, Mb, Wp2b, W2b, W1b, bp1p,
                                       b1, b2, bp2, OUT);
}

// Round 3
// 179.861 us; speedup vs baseline: 1.0870x; 1.0870x over previous
//
#include <hip/hip_runtime.h>
#include <hip/hip_bf16.h>
#include <stdint.h>

typedef __attribute__((ext_vector_type(8))) short short8;
typedef __attribute__((ext_vector_type(4))) float f32x4;
typedef __attribute__((ext_vector_type(4))) unsigned int u32x4;
typedef __attribute__((ext_vector_type(2))) unsigned int u32x2;

// Skeleton (fixed in reference)
__constant__ __align__(16) int NBRC[17][4] = {
    {7, 1, 4, 0}, {0, 2, 0, 0}, {1, 3, 0, 0}, {2, 0, 0, 0},
    {0, 5, 0, 0}, {4, 6, 0, 0}, {5, 0, 0, 0}, {0, 8, 0, 0},
    {7, 9, 11, 14}, {8, 10, 0, 0}, {9, 0, 0, 0}, {8, 12, 0, 0},
    {11, 13, 0, 0}, {12, 0, 0, 0}, {8, 15, 0, 0}, {14, 16, 0, 0},
    {15, 0, 0, 0}};
__constant__ int DEGC[17] = {3,2,2,1,2,2,1,2,4,2,1,2,2,1,2,2,1};
__constant__ float RDEGC[5] = {0.f, 1.f, 0.5f, 0.33333334f, 0.25f};
// per-wave output-joint-tile assignment, balanced so sum(deg) = 8 per wave
__constant__ int WNT[4] = {3, 4, 5, 5};
__constant__ int WJT[4][5] = {{8, 1, 2, 0, 0},
                              {0, 4, 5, 3, 0},
                              {7, 9, 11, 6, 10},
                              {12, 14, 15, 13, 16}};

__device__ inline unsigned short f2bf(float f) {
  union { float f; uint32_t u; } v; v.f = f;
  uint32_t u = v.u;
  uint32_t r = u + 0x7fffu + ((u >> 16) & 1u);  // RNE
  return (unsigned short)(r >> 16);
}
// hardware v_cvt_pk_bf16_f32 (RNE), a in low 16, b in high 16
__device__ inline uint32_t pk2(float a, float b) {
  union { __hip_bfloat162 h; uint32_t u; } v;
  v.h = __float22bfloat162_rn(make_float2(a, b));
  return v.u;
}
__device__ inline f32x4 mfma16(short8 a, short8 b, f32x4 c) {
  return __builtin_amdgcn_mfma_f32_16x16x32_bf16(a, b, c, 0, 0, 0);
}

// ---------------- prep kernel (unchanged) ----------------
__global__ void prep(const float* __restrict__ W1,
                     const float* __restrict__ W2,
                     const float* __restrict__ Wp2,
                     const float* __restrict__ W3,
                     const float* __restrict__ Wp1,
                     const float* __restrict__ b3,
                     const float* __restrict__ bp1,
                     short* __restrict__ W1b,
                     short* __restrict__ W2b,
                     short* __restrict__ Wp2b,
                     short* __restrict__ Mb,
                     float* __restrict__ bp1p) {
  __shared__ float w3s[4096];
  __shared__ float Qs[256];
  const int tid = threadIdx.x;
  const int bx = blockIdx.x;
  if (bx < 272) {
    for (int q = tid; q < 4096; q += 256) w3s[q] = W3[q];
    {
      int ro = tid >> 6, k = tid & 63;
      int r = bx * 4 + ro;
      int f = r / 17, i = r - f * 17;
      int dj = DEGC[i];
      float s = 0.f;
#pragma unroll
      for (int t = 0; t < 4; t++) {
        if (t < dj) {
          int nb = NBRC[i][t];
          s += RDEGC[DEGC[nb]] * Wp1[f * 1088 + nb * 64 + k];
        }
      }
      Qs[ro * 64 + k] = s;
    }
    __syncthreads();
    {
      int ro = tid >> 6, c = tid & 63;
      int r = bx * 4 + ro;
      int f = r / 17, i = r - f * 17;
      float s = 0.f;
#pragma unroll
      for (int k = 0; k < 64; k++) s += Qs[ro * 64 + k] * w3s[k * 64 + c];
      int col = i * 64 + c;
      int kk = col >> 5, qq = (col >> 3) & 3, cb = col & 7;
      int w = f >> 4, l15 = f & 15;
      Mb[(((w * 34 + kk) * 64) + qq * 16 + l15) * 8 + cb] = (short)f2bf(s);
    }
  } else if (bx < 354) {
    int q = (bx - 272) * 256 + tid;
    if (q < 4096) W2b[q] = (short)f2bf(W2[q]);
    int q2 = q - 4096;
    if (q2 >= 0 && q2 < 16384) Wp2b[q2] = (short)f2bf(Wp2[q2]);
    int q3 = q - 20480;
    if (q3 >= 0 && q3 < 512) {
      int k = q3 & 7;
      W1b[q3] = (k < 3) ? (short)f2bf(W1[(q3 >> 3) * 3 + k]) : (short)0;
    }
  } else {
    int wv = tid >> 6, l = tid & 63;
    int f = (bx - 354) * 4 + wv;
    float s = 0.f;
#pragma unroll
    for (int i = 0; i < 17; i++) s += Wp1[f * 1088 + i * 64 + l] * b3[l];
#pragma unroll
    for (int off = 32; off > 0; off >>= 1) s += __shfl_down(s, off);
    if (l == 0) bp1p[f] = bp1[f] + s;
  }
}

// ---------------- main fused kernel ----------------
// 256 threads / 4 waves, 32 elements/block as TWO independent 16-elem tiles
// (g=0,1) carried by every wave through every phase. Rationale (R0-R2
// post-mortems): waves are ~95% stalled on short ds_read->MFMA->pack
// dependency chains; raising occupancy (R1) and cutting barriers/weight
// refetch (R2) were both flat -> attack stalls with intra-wave ILP: two
// independent chains per phase, weight fragments (W1/W2/Mb/Wp2) loaded
// once into registers and used for both tiles. LDS = 69632+6528+768 =
// 76928 B -> 2 blocks/CU; launch_bounds(256,2) allows up to 256 VGPR for
// the dual accumulator set in Layer 2.
__launch_bounds__(256, 2)
__global__ void gcn_main(const float* __restrict__ X,
                         const short* __restrict__ Mb,
                         const short* __restrict__ Wp2b,
                         const short* __restrict__ W2b,
                         const short* __restrict__ W1b,
                         const float* __restrict__ bp1p,
                         const float* __restrict__ b1g,
                         const float* __restrict__ b2g,
                         const float* __restrict__ bp2g,
                         float* __restrict__ OUT) {
  __shared__ __align__(16) short hbuf[2 * 272 * 64];  // 69632 B (2 tiles)
  __shared__ __align__(16) float xs[2 * 816];         // 6528 B; zb overlays late
  __shared__ __align__(16) float sbias[192];          // 768 B: b1|b2|bp1p

  const int tid = threadIdx.x;
  const int wave = tid >> 6;
  const int lane = tid & 63;
  const int ln15 = lane & 15;
  const int quad = lane >> 4;
  const int bx = blockIdx.x;

  auto hswz = [](int row, int cb) { return row * 128 + (cb ^ ((row & 7) << 4)); };

  // ---- init ----
  for (int q = tid; q < 408; q += 256)
    ((f32x4*)xs)[q] = ((const f32x4*)(X + (size_t)bx * 1632))[q];
  short8 w1f[4];
#pragma unroll
  for (int ft = 0; ft < 4; ft++)
    w1f[ft] = *(const short8*)(W1b + (ft * 16 + ln15) * 8);
  if (tid < 192) {
    float v;
    if (tid < 64) v = b1g[tid];
    else if (tid < 128) v = b2g[tid - 64];
    else v = bp1p[tid - 128];
    sbias[tid] = v;
  }
  __syncthreads();  // xs, sbias ready

  auto wb = [&](char* hb, f32x4 c, int j, int ft, int bofs, float scale) {
    int r = j * 16 + ln15;
    int fb = ft * 16 + quad * 4;
    f32x4 bv = *(const f32x4*)&sbias[bofs + fb];
    float v0 = fmaxf(c.x * scale + bv.x, 0.f);
    float v1 = fmaxf(c.y * scale + bv.y, 0.f);
    float v2 = fmaxf(c.z * scale + bv.z, 0.f);
    float v3 = fmaxf(c.w * scale + bv.w, 0.f);
    u32x2 pk;
    pk.x = pk2(v0, v1);
    pk.y = pk2(v2, v3);
    *(u32x2*)(hb + hswz(r, fb * 2)) = pk;
  };

  const int nt = WNT[wave];

  // ---- Layer 1 with fused agg0, both tiles interleaved ----
#pragma unroll
  for (int t = 0; t < 5; t++) {
    if (t < nt) {
      int j = WJT[wave][t];
      int4 nb = *(const int4*)(&NBRC[j][0]);
      int dj = DEGC[j];
      float w = RDEGC[dj];
      union { short8 s; u32x4 u; } fr[2];
#pragma unroll
      for (int g = 0; g < 2; g++) {
        const float* xsg = xs + g * 816;
        fr[g].u = (u32x4){0u, 0u, 0u, 0u};
        if (quad == 0) {
          float s0, s1, s2;
          {
            int b = ln15 * 51 + nb.x * 3;
            s0 = xsg[b]; s1 = xsg[b + 1]; s2 = xsg[b + 2];
          }
          if (dj > 1) {
            int b = ln15 * 51 + nb.y * 3;
            s0 += xsg[b]; s1 += xsg[b + 1]; s2 += xsg[b + 2];
          }
          if (dj > 2) {
            int b = ln15 * 51 + nb.z * 3;
            s0 += xsg[b]; s1 += xsg[b + 1]; s2 += xsg[b + 2];
          }
          if (dj > 3) {
            int b = ln15 * 51 + nb.w * 3;
            s0 += xsg[b]; s1 += xsg[b + 1]; s2 += xsg[b + 2];
          }
          fr[g].u.x = pk2(s0 * w, s1 * w);
          fr[g].u.y = pk2(s2 * w, 0.f);
        }
      }
      f32x4 a[2][4];
#pragma unroll
      for (int g = 0; g < 2; g++)
#pragma unroll
        for (int ft = 0; ft < 4; ft++) {
          f32x4 z = (f32x4){0.f, 0.f, 0.f, 0.f};
          a[g][ft] = mfma16(w1f[ft], fr[g].s, z);
        }
#pragma unroll
      for (int g = 0; g < 2; g++)
#pragma unroll
        for (int ft = 0; ft < 4; ft++)
          wb((char*)hbuf + g * 34816, a[g][ft], j, ft, 0, 1.f);
    }
  }
  __syncthreads();  // h1 ready

  const short8* mrow = ((const short8*)Mb) + (size_t)wave * 34 * 64 + lane;
  short8 pf[8];

  // ---- Layer 2: block-sparse MFMA aggregation, dual-tile, kk-outer ----
  {
    f32x4 acc[2][5][4];
#pragma unroll
    for (int g = 0; g < 2; g++)
#pragma unroll
      for (int t = 0; t < 5; t++)
        if (t < nt)
#pragma unroll
          for (int ft = 0; ft < 4; ft++)
            acc[g][t][ft] = (f32x4){0.f, 0.f, 0.f, 0.f};
#pragma unroll
    for (int kk = 0; kk < 2; kk++) {
      short8 w2f[4];
#pragma unroll
      for (int ft = 0; ft < 4; ft++)
        w2f[ft] = *(const short8*)(W2b + (ft * 16 + ln15) * 64 + kk * 32 + quad * 8);
#pragma unroll
      for (int t = 0; t < 5; t++) {
        if (t < nt) {
          int j = WJT[wave][t];
          int dj = DEGC[j];
#pragma unroll
          for (int s = 0; s < 4; s++) {
            if (s < dj) {
              int i = NBRC[j][s];
#pragma unroll
              for (int g = 0; g < 2; g++) {
                short8 bf = *(const short8*)((char*)hbuf + g * 34816 +
                                             hswz(i * 16 + ln15, kk * 64 + quad * 16));
#pragma unroll
                for (int ft = 0; ft < 4; ft++)
                  acc[g][t][ft] = mfma16(w2f[ft], bf, acc[g][t][ft]);
              }
            }
          }
        }
      }
    }
    __syncthreads();  // all h1 reads done before overwrite
#pragma unroll
    for (int t = 0; t < 5; t++)
      if (t < nt) {
        int j = WJT[wave][t];
        float w = RDEGC[DEGC[j]];
#pragma unroll
        for (int g = 0; g < 2; g++)
#pragma unroll
          for (int ft = 0; ft < 4; ft++)
            wb((char*)hbuf + g * 34816, acc[g][t][ft], j, ft, 64, w);
      }
    // issue pool prefetch before the barrier: L2 latency hides behind sync
#pragma unroll
    for (int p = 0; p < 8; p++) pf[p] = mrow[p * 64];
  }
  __syncthreads();  // h2 ready

  // ---- Pool (folded layer3+pool1): one af stream feeds both tiles ----
  f32x4 zcv[2];
  {
    f32x4 acc[2][2];
#pragma unroll
    for (int g = 0; g < 2; g++) {
      acc[g][0] = (f32x4){0.f, 0.f, 0.f, 0.f};
      acc[g][1] = (f32x4){0.f, 0.f, 0.f, 0.f};
    }
#pragma unroll
    for (int kk = 0; kk < 34; kk++) {
      short8 af = pf[kk & 7];
      if (kk + 8 < 34) pf[kk & 7] = mrow[(kk + 8) * 64];
      int i = kk >> 1;
#pragma unroll
      for (int g = 0; g < 2; g++) {
        short8 bf = *(const short8*)((char*)hbuf + g * 34816 +
                                     hswz(i * 16 + ln15, (kk & 1) * 64 + quad * 16));
        if (kk & 1) acc[g][1] = mfma16(af, bf, acc[g][1]);
        else acc[g][0] = mfma16(af, bf, acc[g][0]);
      }
    }
    zcv[0] = acc[0][0] + acc[0][1];
    zcv[1] = acc[1][0] + acc[1][1];
  }
  // prefetch Wp2 fragments (shared across tiles); hides behind zb pack+barrier
  short8 wp2f[4][2];
#pragma unroll
  for (int t = 0; t < 4; t++) {
    int ot = wave + 4 * t;
    wp2f[t][0] = *(const short8*)(Wp2b + (ot * 16 + ln15) * 64 + quad * 8);
    wp2f[t][1] = *(const short8*)(Wp2b + (ot * 16 + ln15) * 64 + 32 + quad * 8);
  }
#pragma unroll
  for (int g = 0; g < 2; g++) {
    char* zbB = (char*)(xs + g * 816);  // overlay: xs dead since L1
    int fb = wave * 16 + quad * 4;
    f32x4 bv = *(const f32x4*)&sbias[128 + fb];
    float v0 = fmaxf(zcv[g].x + bv.x, 0.f);
    float v1 = fmaxf(zcv[g].y + bv.y, 0.f);
    float v2 = fmaxf(zcv[g].z + bv.z, 0.f);
    float v3 = fmaxf(zcv[g].w + bv.w, 0.f);
    u32x2 pk;
    pk.x = pk2(v0, v1);
    pk.y = pk2(v2, v3);
    *(u32x2*)(zbB + hswz(ln15, fb * 2)) = pk;
  }
  __syncthreads();  // zb ready

  // ---- Pool layer 2: out = Wp2 * z + bp2, both tiles ----
#pragma unroll
  for (int g = 0; g < 2; g++) {
    char* zbB = (char*)(xs + g * 816);
    short8 bf0 = *(const short8*)(zbB + hswz(ln15, quad * 16));
    short8 bf1 = *(const short8*)(zbB + hswz(ln15, 64 + quad * 16));
    int e0g = bx * 32 + g * 16;
#pragma unroll
    for (int t = 0; t < 4; t++) {
      int ot = wave + 4 * t;
      f32x4 a = (f32x4){0.f, 0.f, 0.f, 0.f};
      a = mfma16(wp2f[t][0], bf0, a);
      a = mfma16(wp2f[t][1], bf1, a);
      int ob = ot * 16 + quad * 4;
      f32x4 bv = *(const f32x4*)&bp2g[ob];
      f32x4 res = a + bv;
      *(f32x4*)(OUT + (size_t)(e0g + ln15) * 256 + ob) = res;
    }
  }
}

extern "C" void kernel_launch(void* const* d_in, const int* in_sizes, int n_in,
                              void* d_out, int out_size, void* d_ws, size_t ws_size,
                              hipStream_t stream) {
  const float* X = (const float*)d_in[0];
  const float* W1 = (const float*)d_in[2];
  const float* b1 = (const float*)d_in[3];
  const float* W2 = (const float*)d_in[4];
  const float* b2 = (const float*)d_in[5];
  const float* W3 = (const float*)d_in[6];
  const float* b3 = (const float*)d_in[7];
  const float* Wp1 = (const float*)d_in[8];
  const float* bp1 = (const float*)d_in[9];
  const float* Wp2 = (const float*)d_in[10];
  const float* bp2 = (const float*)d_in[11];
  float* OUT = (float*)d_out;
  const int B = in_sizes[0] / 51;

  char* ws = (char*)d_ws;
  short* Mb = (short*)(ws + 0);          // 64*1088*2 = 139264 (swizzled)
  short* Wp2b = (short*)(ws + 139264);   // 32768
  short* W2b = (short*)(ws + 172032);    // 8192
  short* W1b = (short*)(ws + 180224);    // 1024
  float* bp1p = (float*)(ws + 181248);   // 256

  prep<<<370, 256, 0, stream>>>(W1, W2, Wp2, W3, Wp1, b3, bp1,
                                W1b, W2b, Wp2b, Mb, bp1p);
  gcn_main<<<B / 32, 256, 0, stream>>>(X, Mb, Wp2b, W2b, W1b, bp1p,
                                       b1, b2, bp2, OUT);
}

// Round 4
// 173.790 us; speedup vs baseline: 1.1250x; 1.0349x over previous
//
#include <hip/hip_runtime.h>
#include <hip/hip_bf16.h>
#include <stdint.h>

typedef __attribute__((ext_vector_type(8))) short short8;
typedef __attribute__((ext_vector_type(4))) float f32x4;
typedef __attribute__((ext_vector_type(4))) unsigned int u32x4;
typedef __attribute__((ext_vector_type(2))) unsigned int u32x2;

// Skeleton (fixed in reference) — constexpr so wave-specialized code folds
// every index/degree/offset into immediates (no constant-mem loads in hot
// loops; that was the R3 stall suspect).
constexpr int kNBR[17][4] = {
    {7, 1, 4, 0}, {0, 2, 0, 0}, {1, 3, 0, 0}, {2, 0, 0, 0},
    {0, 5, 0, 0}, {4, 6, 0, 0}, {5, 0, 0, 0}, {0, 8, 0, 0},
    {7, 9, 11, 14}, {8, 10, 0, 0}, {9, 0, 0, 0}, {8, 12, 0, 0},
    {11, 13, 0, 0}, {12, 0, 0, 0}, {8, 15, 0, 0}, {14, 16, 0, 0},
    {15, 0, 0, 0}};
constexpr int kDEG[17] = {3,2,2,1,2,2,1,2,4,2,1,2,2,1,2,2,1};
constexpr float kRDEG[5] = {0.f, 1.f, 0.5f, 0.33333334f, 0.25f};
// per-wave output-joint tiles, balanced so sum(deg) = 8 per wave
constexpr int kWNT[4] = {3, 4, 5, 5};
constexpr int kWJT[4][5] = {{8, 1, 2, 0, 0},
                            {0, 4, 5, 3, 0},
                            {7, 9, 11, 6, 10},
                            {12, 14, 15, 13, 16}};

template <int N> struct IC { static constexpr int v = N; };

__device__ inline unsigned short f2bf(float f) {
  union { float f; uint32_t u; } v; v.f = f;
  uint32_t u = v.u;
  uint32_t r = u + 0x7fffu + ((u >> 16) & 1u);  // RNE
  return (unsigned short)(r >> 16);
}
// hardware v_cvt_pk_bf16_f32 (RNE), a in low 16, b in high 16
__device__ inline uint32_t pk2(float a, float b) {
  union { __hip_bfloat162 h; uint32_t u; } v;
  v.h = __float22bfloat162_rn(make_float2(a, b));
  return v.u;
}
__device__ inline f32x4 mfma16(short8 a, short8 b, f32x4 c) {
  return __builtin_amdgcn_mfma_f32_16x16x32_bf16(a, b, c, 0, 0, 0);
}

// ---------------- prep kernel ----------------
// (b1 now baked into W1b's spare K-slot k=3; main kernel's L1 B-fragment
// supplies 1.0 at k=3, so L1 epilogue is pure relu+pack.)
__global__ void prep(const float* __restrict__ W1,
                     const float* __restrict__ W2,
                     const float* __restrict__ Wp2,
                     const float* __restrict__ W3,
                     const float* __restrict__ Wp1,
                     const float* __restrict__ b3,
                     const float* __restrict__ bp1,
                     const float* __restrict__ b1,
                     short* __restrict__ W1b,
                     short* __restrict__ W2b,
                     short* __restrict__ Wp2b,
                     short* __restrict__ Mb,
                     float* __restrict__ bp1p) {
  __shared__ float w3s[4096];
  __shared__ float Qs[256];
  const int tid = threadIdx.x;
  const int bx = blockIdx.x;
  if (bx < 272) {
    for (int q = tid; q < 4096; q += 256) w3s[q] = W3[q];
    {
      int ro = tid >> 6, k = tid & 63;
      int r = bx * 4 + ro;
      int f = r / 17, i = r - f * 17;
      int dj = kDEG[i];
      float s = 0.f;
#pragma unroll
      for (int t = 0; t < 4; t++) {
        if (t < dj) {
          int nb = kNBR[i][t];
          s += kRDEG[kDEG[nb]] * Wp1[f * 1088 + nb * 64 + k];
        }
      }
      Qs[ro * 64 + k] = s;
    }
    __syncthreads();
    {
      int ro = tid >> 6, c = tid & 63;
      int r = bx * 4 + ro;
      int f = r / 17, i = r - f * 17;
      float s = 0.f;
#pragma unroll
      for (int k = 0; k < 64; k++) s += Qs[ro * 64 + k] * w3s[k * 64 + c];
      int col = i * 64 + c;
      int kk = col >> 5, qq = (col >> 3) & 3, cb = col & 7;
      int w = f >> 4, l15 = f & 15;
      Mb[(((w * 34 + kk) * 64) + qq * 16 + l15) * 8 + cb] = (short)f2bf(s);
    }
  } else if (bx < 354) {
    int q = (bx - 272) * 256 + tid;
    if (q < 4096) W2b[q] = (short)f2bf(W2[q]);
    int q2 = q - 4096;
    if (q2 >= 0 && q2 < 16384) Wp2b[q2] = (short)f2bf(Wp2[q2]);
    int q3 = q - 20480;
    if (q3 >= 0 && q3 < 512) {
      int k = q3 & 7, row = q3 >> 3;
      short v = 0;
      if (k < 3) v = (short)f2bf(W1[row * 3 + k]);
      else if (k == 3) v = (short)f2bf(b1[row]);  // bias in spare K-slot
      W1b[q3] = v;
    }
  } else {
    int wv = tid >> 6, l = tid & 63;
    int f = (bx - 354) * 4 + wv;
    float s = 0.f;
#pragma unroll
    for (int i = 0; i < 17; i++) s += Wp1[f * 1088 + i * 64 + l] * b3[l];
#pragma unroll
    for (int off = 32; off > 0; off >>= 1) s += __shfl_down(s, off);
    if (l == 0) bp1p[f] = bp1[f] + s;
  }
}

// ---------------- main fused kernel ----------------
// 256 threads / 4 waves, dual 16-elem tiles per wave (R3 ILP structure).
// R4: wave-specialized L1/L2 via compile-time dispatch — all joint
// indices/degrees/neighbors/LDS offsets are immediates; no __constant__
// loads or data-dependent branches in hot loops. Barriers stay at top
// level (outside the divergent dispatch). LDS = 69632+6528+512 B ->
// 2 blocks/CU.
__launch_bounds__(256, 2)
__global__ void gcn_main(const float* __restrict__ X,
                         const short* __restrict__ Mb,
                         const short* __restrict__ Wp2b,
                         const short* __restrict__ W2b,
                         const short* __restrict__ W1b,
                         const float* __restrict__ bp1p,
                         const float* __restrict__ b2g,
                         const float* __restrict__ bp2g,
                         float* __restrict__ OUT) {
  __shared__ __align__(16) short hbuf[2 * 272 * 64];  // 69632 B (2 tiles)
  __shared__ __align__(16) float xs[2 * 816];         // 6528 B; zb overlays late
  __shared__ __align__(16) float sbias[128];          // b2 | bp1p

  const int tid = threadIdx.x;
  const int wave = tid >> 6;
  const int lane = tid & 63;
  const int ln15 = lane & 15;
  const int quad = lane >> 4;
  const int bx = blockIdx.x;

  auto hswz = [](int row, int cb) { return row * 128 + (cb ^ ((row & 7) << 4)); };

  // ---- init ----
  for (int q = tid; q < 408; q += 256)
    ((f32x4*)xs)[q] = ((const f32x4*)(X + (size_t)bx * 1632))[q];
  short8 w1f[4];
#pragma unroll
  for (int ft = 0; ft < 4; ft++)
    w1f[ft] = *(const short8*)(W1b + (ft * 16 + ln15) * 8);
  if (tid < 128) {
    sbias[tid] = (tid < 64) ? b2g[tid] : bp1p[tid - 64];
  }
  __syncthreads();  // xs, sbias ready

  f32x4 acc[2][5][4];  // L2 accumulators (only [0..NT) used per wave; static idx)

  // ---- Layer 1 (fused agg0; bias via K-slot; relu+pack epilogue) ----
  auto l1 = [&](auto wv) {
    constexpr int WV = decltype(wv)::v;
    constexpr int NT = kWNT[WV];
#pragma unroll
    for (int t = 0; t < NT; t++) {
      const int j = kWJT[WV][t];
      const int dj = kDEG[j];
      const float w = kRDEG[dj];
      union { short8 s; u32x4 u; } fr[2];
#pragma unroll
      for (int g = 0; g < 2; g++) {
        const float* xsg = xs + g * 816;
        fr[g].u = (u32x4){0u, 0u, 0u, 0u};
        if (quad == 0) {
          float s0, s1, s2;
          {
            int b = ln15 * 51 + kNBR[j][0] * 3;
            s0 = xsg[b]; s1 = xsg[b + 1]; s2 = xsg[b + 2];
          }
          if (dj > 1) {
            int b = ln15 * 51 + kNBR[j][1] * 3;
            s0 += xsg[b]; s1 += xsg[b + 1]; s2 += xsg[b + 2];
          }
          if (dj > 2) {
            int b = ln15 * 51 + kNBR[j][2] * 3;
            s0 += xsg[b]; s1 += xsg[b + 1]; s2 += xsg[b + 2];
          }
          if (dj > 3) {
            int b = ln15 * 51 + kNBR[j][3] * 3;
            s0 += xsg[b]; s1 += xsg[b + 1]; s2 += xsg[b + 2];
          }
          fr[g].u.x = pk2(s0 * w, s1 * w);
          fr[g].u.y = pk2(s2 * w, 1.0f);  // k=3 = 1.0 activates bias row
        }
      }
#pragma unroll
      for (int g = 0; g < 2; g++) {
        f32x4 a[4];
#pragma unroll
        for (int ft = 0; ft < 4; ft++)
          a[ft] = mfma16(w1f[ft], fr[g].s, (f32x4){0.f, 0.f, 0.f, 0.f});
#pragma unroll
        for (int ft = 0; ft < 4; ft++) {
          int fb = ft * 16 + quad * 4;
          u32x2 pk;
          pk.x = pk2(fmaxf(a[ft].x, 0.f), fmaxf(a[ft].y, 0.f));
          pk.y = pk2(fmaxf(a[ft].z, 0.f), fmaxf(a[ft].w, 0.f));
          *(u32x2*)((char*)hbuf + g * 34816 + hswz(j * 16 + ln15, fb * 2)) = pk;
        }
      }
    }
  };

  // ---- Layer 2 MFMA (reads h1 of compile-time neighbors) ----
  auto l2m = [&](auto wv) {
    constexpr int WV = decltype(wv)::v;
    constexpr int NT = kWNT[WV];
#pragma unroll
    for (int g = 0; g < 2; g++)
#pragma unroll
      for (int t = 0; t < NT; t++)
#pragma unroll
        for (int ft = 0; ft < 4; ft++)
          acc[g][t][ft] = (f32x4){0.f, 0.f, 0.f, 0.f};
#pragma unroll
    for (int kk = 0; kk < 2; kk++) {
      short8 w2f[4];
#pragma unroll
      for (int ft = 0; ft < 4; ft++)
        w2f[ft] = *(const short8*)(W2b + (ft * 16 + ln15) * 64 + kk * 32 + quad * 8);
#pragma unroll
      for (int t = 0; t < NT; t++) {
        const int j = kWJT[WV][t];
#pragma unroll
        for (int s = 0; s < 4; s++) {
          if (s < kDEG[j]) {
            const int i = kNBR[j][s];
#pragma unroll
            for (int g = 0; g < 2; g++) {
              short8 bf = *(const short8*)((char*)hbuf + g * 34816 +
                                           hswz(i * 16 + ln15, kk * 64 + quad * 16));
#pragma unroll
              for (int ft = 0; ft < 4; ft++)
                acc[g][t][ft] = mfma16(w2f[ft], bf, acc[g][t][ft]);
            }
          }
        }
      }
    }
  };

  // ---- Layer 2 writeback (scale + b2 + relu + pack) ----
  auto l2wb = [&](auto wv) {
    constexpr int WV = decltype(wv)::v;
    constexpr int NT = kWNT[WV];
#pragma unroll
    for (int t = 0; t < NT; t++) {
      const int j = kWJT[WV][t];
      const float w = kRDEG[kDEG[j]];
#pragma unroll
      for (int g = 0; g < 2; g++)
#pragma unroll
        for (int ft = 0; ft < 4; ft++) {
          int fb = ft * 16 + quad * 4;
          f32x4 bv = *(const f32x4*)&sbias[fb];
          f32x4 c = acc[g][t][ft];
          u32x2 pk;
          pk.x = pk2(fmaxf(c.x * w + bv.x, 0.f), fmaxf(c.y * w + bv.y, 0.f));
          pk.y = pk2(fmaxf(c.z * w + bv.z, 0.f), fmaxf(c.w * w + bv.w, 0.f));
          *(u32x2*)((char*)hbuf + g * 34816 + hswz(j * 16 + ln15, fb * 2)) = pk;
        }
    }
  };

#define WDISPATCH(F)                       \
  do {                                     \
    if (wave == 0) F(IC<0>{});             \
    else if (wave == 1) F(IC<1>{});        \
    else if (wave == 2) F(IC<2>{});        \
    else F(IC<3>{});                       \
  } while (0)

  WDISPATCH(l1);
  __syncthreads();  // h1 ready
  WDISPATCH(l2m);
  __syncthreads();  // all h1 reads done before overwrite

  // pool prefetch issued early: overlaps with l2wb VALU + barrier
  const short8* mrow = ((const short8*)Mb) + (size_t)wave * 34 * 64 + lane;
  short8 pf[12];
#pragma unroll
  for (int p = 0; p < 12; p++) pf[p] = mrow[p * 64];

  WDISPATCH(l2wb);
  __syncthreads();  // h2 ready
#undef WDISPATCH

  // ---- Pool (folded layer3+pool1): 4 acc chains/tile, bias in chain 0 ----
  const int fbw = wave * 16 + quad * 4;
  f32x4 zcv[2];
  {
    f32x4 bvp = *(const f32x4*)&sbias[64 + fbw];
    f32x4 pacc[2][4];
#pragma unroll
    for (int g = 0; g < 2; g++) {
      pacc[g][0] = bvp;
      pacc[g][1] = (f32x4){0.f, 0.f, 0.f, 0.f};
      pacc[g][2] = (f32x4){0.f, 0.f, 0.f, 0.f};
      pacc[g][3] = (f32x4){0.f, 0.f, 0.f, 0.f};
    }
#pragma unroll
    for (int kk = 0; kk < 34; kk++) {
      short8 af = pf[kk % 12];
      if (kk + 12 < 34) pf[kk % 12] = mrow[(kk + 12) * 64];
      int i = kk >> 1;
#pragma unroll
      for (int g = 0; g < 2; g++) {
        short8 bf = *(const short8*)((char*)hbuf + g * 34816 +
                                     hswz(i * 16 + ln15, (kk & 1) * 64 + quad * 16));
        pacc[g][kk & 3] = mfma16(af, bf, pacc[g][kk & 3]);
      }
    }
    zcv[0] = (pacc[0][0] + pacc[0][1]) + (pacc[0][2] + pacc[0][3]);
    zcv[1] = (pacc[1][0] + pacc[1][1]) + (pacc[1][2] + pacc[1][3]);
  }
  // prefetch Wp2 fragments; latency hides behind zb pack + barrier
  short8 wp2f[4][2];
#pragma unroll
  for (int t = 0; t < 4; t++) {
    int ot = wave + 4 * t;
    wp2f[t][0] = *(const short8*)(Wp2b + (ot * 16 + ln15) * 64 + quad * 8);
    wp2f[t][1] = *(const short8*)(Wp2b + (ot * 16 + ln15) * 64 + 32 + quad * 8);
  }
#pragma unroll
  for (int g = 0; g < 2; g++) {
    char* zbB = (char*)(xs + g * 816);  // overlay: xs dead since L1
    u32x2 pk;
    pk.x = pk2(fmaxf(zcv[g].x, 0.f), fmaxf(zcv[g].y, 0.f));
    pk.y = pk2(fmaxf(zcv[g].z, 0.f), fmaxf(zcv[g].w, 0.f));
    *(u32x2*)(zbB + hswz(ln15, fbw * 2)) = pk;
  }
  __syncthreads();  // zb ready

  // ---- Pool layer 2: out = Wp2 * z + bp2, both tiles ----
#pragma unroll
  for (int g = 0; g < 2; g++) {
    char* zbB = (char*)(xs + g * 816);
    short8 bf0 = *(const short8*)(zbB + hswz(ln15, quad * 16));
    short8 bf1 = *(const short8*)(zbB + hswz(ln15, 64 + quad * 16));
    int e0g = bx * 32 + g * 16;
#pragma unroll
    for (int t = 0; t < 4; t++) {
      int ot = wave + 4 * t;
      f32x4 a = (f32x4){0.f, 0.f, 0.f, 0.f};
      a = mfma16(wp2f[t][0], bf0, a);
      a = mfma16(wp2f[t][1], bf1, a);
      int ob = ot * 16 + quad * 4;
      f32x4 bv = *(const f32x4*)&bp2g[ob];
      f32x4 res = a + bv;
      *(f32x4*)(OUT + (size_t)(e0g + ln15) * 256 + ob) = res;
    }
  }
}

extern "C" void kernel_launch(void* const* d_in, const int* in_sizes, int n_in,
                              void* d_out, int out_size, void* d_ws, size_t ws_size,
                              hipStream_t stream) {
  const float* X = (const float*)d_in[0];
  const float* W1 = (const float*)d_in[2];
  const float* b1 = (const float*)d_in[3];
  const float* W2 = (const float*)d_in[4];
  const float* b2 = (const float*)d_in[5];
  const float* W3 = (const float*)d_in[6];
  const float* b3 = (const float*)d_in[7];
  const float* Wp1 = (const float*)d_in[8];
  const float* bp1 = (const float*)d_in[9];
  const float* Wp2 = (const float*)d_in[10];
  const float* bp2 = (const float*)d_in[11];
  float* OUT = (float*)d_out;
  const int B = in_sizes[0] / 51;

  char* ws = (char*)d_ws;
  short* Mb = (short*)(ws + 0);          // 64*1088*2 = 139264 (swizzled)
  short* Wp2b = (short*)(ws + 139264);   // 32768
  short* W2b = (short*)(ws + 172032);    // 8192
  short* W1b = (short*)(ws + 180224);    // 1024 (k=3 slot = b1)
  float* bp1p = (float*)(ws + 181248);   // 256

  prep<<<370, 256, 0, stream>>>(W1, W2, Wp2, W3, Wp1, b3, bp1, b1,
                                W1b, W2b, Wp2b, Mb, bp1p);
  gcn_main<<<B / 32, 256, 0, stream>>>(X, Mb, Wp2b, W2b, W1b, bp1p,
                                       b2, bp2, OUT);
}

// Round 5
// 155.244 us; speedup vs baseline: 1.2593x; 1.1195x over previous
//
#include <hip/hip_runtime.h>
#include <hip/hip_bf16.h>
#include <stdint.h>

typedef __attribute__((ext_vector_type(8))) short short8;
typedef __attribute__((ext_vector_type(4))) float f32x4;
typedef __attribute__((ext_vector_type(4))) unsigned int u32x4;
typedef __attribute__((ext_vector_type(2))) unsigned int u32x2;

// Skeleton (fixed in reference) — constexpr so wave-specialized code folds
// every index/degree/offset into immediates.
constexpr int kNBR[17][4] = {
    {7, 1, 4, 0}, {0, 2, 0, 0}, {1, 3, 0, 0}, {2, 0, 0, 0},
    {0, 5, 0, 0}, {4, 6, 0, 0}, {5, 0, 0, 0}, {0, 8, 0, 0},
    {7, 9, 11, 14}, {8, 10, 0, 0}, {9, 0, 0, 0}, {8, 12, 0, 0},
    {11, 13, 0, 0}, {12, 0, 0, 0}, {8, 15, 0, 0}, {14, 16, 0, 0},
    {15, 0, 0, 0}};
constexpr int kDEG[17] = {3,2,2,1,2,2,1,2,4,2,1,2,2,1,2,2,1};
constexpr float kRDEG[5] = {0.f, 1.f, 0.5f, 0.33333334f, 0.25f};
// per-wave output-joint tiles, balanced so sum(deg) = 8 per wave
constexpr int kWNT[4] = {3, 4, 5, 5};
constexpr int kWJT[4][5] = {{8, 1, 2, 0, 0},
                            {0, 4, 5, 3, 0},
                            {7, 9, 11, 6, 10},
                            {12, 14, 15, 13, 16}};

__device__ inline unsigned short f2bf(float f) {
  union { float f; uint32_t u; } v; v.f = f;
  uint32_t u = v.u;
  uint32_t r = u + 0x7fffu + ((u >> 16) & 1u);  // RNE
  return (unsigned short)(r >> 16);
}
// hardware v_cvt_pk_bf16_f32 (RNE), a in low 16, b in high 16
__device__ inline uint32_t pk2(float a, float b) {
  union { __hip_bfloat162 h; uint32_t u; } v;
  v.h = __float22bfloat162_rn(make_float2(a, b));
  return v.u;
}
__device__ inline f32x4 mfma16(short8 a, short8 b, f32x4 c) {
  return __builtin_amdgcn_mfma_f32_16x16x32_bf16(a, b, c, 0, 0, 0);
}
__device__ inline int hswz(int row, int cb) {
  return row * 128 + (cb ^ ((row & 7) << 4));
}

// ---------------- prep kernel (unchanged from R4) ----------------
__global__ void prep(const float* __restrict__ W1,
                     const float* __restrict__ W2,
                     const float* __restrict__ Wp2,
                     const float* __restrict__ W3,
                     const float* __restrict__ Wp1,
                     const float* __restrict__ b3,
                     const float* __restrict__ bp1,
                     const float* __restrict__ b1,
                     short* __restrict__ W1b,
                     short* __restrict__ W2b,
                     short* __restrict__ Wp2b,
                     short* __restrict__ Mb,
                     float* __restrict__ bp1p) {
  __shared__ float w3s[4096];
  __shared__ float Qs[256];
  const int tid = threadIdx.x;
  const int bx = blockIdx.x;
  if (bx < 272) {
    for (int q = tid; q < 4096; q += 256) w3s[q] = W3[q];
    {
      int ro = tid >> 6, k = tid & 63;
      int r = bx * 4 + ro;
      int f = r / 17, i = r - f * 17;
      int dj = kDEG[i];
      float s = 0.f;
#pragma unroll
      for (int t = 0; t < 4; t++) {
        if (t < dj) {
          int nb = kNBR[i][t];
          s += kRDEG[kDEG[nb]] * Wp1[f * 1088 + nb * 64 + k];
        }
      }
      Qs[ro * 64 + k] = s;
    }
    __syncthreads();
    {
      int ro = tid >> 6, c = tid & 63;
      int r = bx * 4 + ro;
      int f = r / 17, i = r - f * 17;
      float s = 0.f;
#pragma unroll
      for (int k = 0; k < 64; k++) s += Qs[ro * 64 + k] * w3s[k * 64 + c];
      int col = i * 64 + c;
      int kk = col >> 5, qq = (col >> 3) & 3, cb = col & 7;
      int w = f >> 4, l15 = f & 15;
      Mb[(((w * 34 + kk) * 64) + qq * 16 + l15) * 8 + cb] = (short)f2bf(s);
    }
  } else if (bx < 354) {
    int q = (bx - 272) * 256 + tid;
    if (q < 4096) W2b[q] = (short)f2bf(W2[q]);
    int q2 = q - 4096;
    if (q2 >= 0 && q2 < 16384) Wp2b[q2] = (short)f2bf(Wp2[q2]);
    int q3 = q - 20480;
    if (q3 >= 0 && q3 < 512) {
      int k = q3 & 7, row = q3 >> 3;
      short v = 0;
      if (k < 3) v = (short)f2bf(W1[row * 3 + k]);
      else if (k == 3) v = (short)f2bf(b1[row]);  // bias in spare K-slot
      W1b[q3] = v;
    }
  } else {
    int wv = tid >> 6, l = tid & 63;
    int f = (bx - 354) * 4 + wv;
    float s = 0.f;
#pragma unroll
    for (int i = 0; i < 17; i++) s += Wp1[f * 1088 + i * 64 + l] * b3[l];
#pragma unroll
    for (int off = 32; off > 0; off >>= 1) s += __shfl_down(s, off);
    if (l == 0) bp1p[f] = bp1[f] + s;
  }
}

// ---------------- per-wave specialized body ----------------
// Contains the whole post-init flow, barriers included. All waves execute
// the identical barrier sequence (gfx950 s_barrier counts wave arrivals,
// PC-independent), so barrier-in-divergent-dispatch is safe. All register
// arrays are local with static indices -> clean SROA (R4's spill fix).
template <int WV>
__device__ __forceinline__ void waveBody(
    const short* __restrict__ Mb, const short* __restrict__ Wp2b,
    const short* __restrict__ W2b, const float* __restrict__ bp2g,
    float* __restrict__ OUT, short* hbuf, float* xs, float* sbias,
    const short8 (&w1f)[4], int bx, int lane, int ln15, int quad) {
  constexpr int NT = kWNT[WV];
  char* hb0 = (char*)hbuf;

  // ---- Layer 1 (fused agg0; bias via K-slot; relu+pack epilogue) ----
#pragma unroll
  for (int t = 0; t < NT; t++) {
    const int j = kWJT[WV][t];
    const int dj = kDEG[j];
    const float w = kRDEG[dj];
    union { short8 s; u32x4 u; } fr[2];
#pragma unroll
    for (int g = 0; g < 2; g++) {
      const float* xsg = xs + g * 816;
      fr[g].u = (u32x4){0u, 0u, 0u, 0u};
      if (quad == 0) {
        float s0, s1, s2;
        {
          int b = ln15 * 51 + kNBR[j][0] * 3;
          s0 = xsg[b]; s1 = xsg[b + 1]; s2 = xsg[b + 2];
        }
        if (dj > 1) {
          int b = ln15 * 51 + kNBR[j][1] * 3;
          s0 += xsg[b]; s1 += xsg[b + 1]; s2 += xsg[b + 2];
        }
        if (dj > 2) {
          int b = ln15 * 51 + kNBR[j][2] * 3;
          s0 += xsg[b]; s1 += xsg[b + 1]; s2 += xsg[b + 2];
        }
        if (dj > 3) {
          int b = ln15 * 51 + kNBR[j][3] * 3;
          s0 += xsg[b]; s1 += xsg[b + 1]; s2 += xsg[b + 2];
        }
        fr[g].u.x = pk2(s0 * w, s1 * w);
        fr[g].u.y = pk2(s2 * w, 1.0f);  // k=3 = 1.0 activates bias row
      }
    }
#pragma unroll
    for (int g = 0; g < 2; g++) {
      f32x4 a[4];
#pragma unroll
      for (int ft = 0; ft < 4; ft++)
        a[ft] = mfma16(w1f[ft], fr[g].s, (f32x4){0.f, 0.f, 0.f, 0.f});
#pragma unroll
      for (int ft = 0; ft < 4; ft++) {
        int fb = ft * 16 + quad * 4;
        u32x2 pk;
        pk.x = pk2(fmaxf(a[ft].x, 0.f), fmaxf(a[ft].y, 0.f));
        pk.y = pk2(fmaxf(a[ft].z, 0.f), fmaxf(a[ft].w, 0.f));
        *(u32x2*)(hb0 + g * 34816 + hswz(j * 16 + ln15, fb * 2)) = pk;
      }
    }
  }
  __syncthreads();  // h1 ready

  // ---- Layer 2: accumulate per (t,g), pack IMMEDIATELY (only packed
  // u32x2 state crosses the barrier: 2*NT*4*2 regs, half of f32 acc) ----
  short8 w2f[2][4];
#pragma unroll
  for (int kk = 0; kk < 2; kk++)
#pragma unroll
    for (int ft = 0; ft < 4; ft++)
      w2f[kk][ft] = *(const short8*)(W2b + (ft * 16 + ln15) * 64 + kk * 32 + quad * 8);

  u32x2 pkh2[2][NT][4];
#pragma unroll
  for (int t = 0; t < NT; t++) {
    const int j = kWJT[WV][t];
    const int dj = kDEG[j];
    const float w = kRDEG[dj];
#pragma unroll
    for (int g = 0; g < 2; g++) {
      f32x4 a[4];
#pragma unroll
      for (int ft = 0; ft < 4; ft++) a[ft] = (f32x4){0.f, 0.f, 0.f, 0.f};
#pragma unroll
      for (int kk = 0; kk < 2; kk++)
#pragma unroll
        for (int s = 0; s < 4; s++)
          if (s < dj) {
            const int i = kNBR[j][s];
            short8 bf = *(const short8*)(hb0 + g * 34816 +
                                         hswz(i * 16 + ln15, kk * 64 + quad * 16));
#pragma unroll
            for (int ft = 0; ft < 4; ft++)
              a[ft] = mfma16(w2f[kk][ft], bf, a[ft]);
          }
#pragma unroll
      for (int ft = 0; ft < 4; ft++) {
        int fb = ft * 16 + quad * 4;
        f32x4 bv = *(const f32x4*)&sbias[fb];
        u32x2 pk;
        pk.x = pk2(fmaxf(a[ft].x * w + bv.x, 0.f), fmaxf(a[ft].y * w + bv.y, 0.f));
        pk.y = pk2(fmaxf(a[ft].z * w + bv.z, 0.f), fmaxf(a[ft].w * w + bv.w, 0.f));
        pkh2[g][t][ft] = pk;
      }
    }
  }
  // pool prefetch issued before the WAR barrier: L2 latency hides behind it
  const short8* mrow = ((const short8*)Mb) + (size_t)WV * 34 * 64 + lane;
  short8 pf[8];
#pragma unroll
  for (int p = 0; p < 8; p++) pf[p] = mrow[p * 64];
  __syncthreads();  // all h1 reads done before overwrite

  // ---- h2 writeback (pure ds_writes of prepacked values) ----
#pragma unroll
  for (int t = 0; t < NT; t++) {
    const int j = kWJT[WV][t];
#pragma unroll
    for (int g = 0; g < 2; g++)
#pragma unroll
      for (int ft = 0; ft < 4; ft++) {
        int fb = ft * 16 + quad * 4;
        *(u32x2*)(hb0 + g * 34816 + hswz(j * 16 + ln15, fb * 2)) = pkh2[g][t][ft];
      }
  }
  __syncthreads();  // h2 ready

  // ---- Pool (folded layer3+pool1): 4 acc chains/tile, bias in chain 0 ----
  const int fbw = WV * 16 + quad * 4;
  f32x4 zcv[2];
  {
    f32x4 bvp = *(const f32x4*)&sbias[64 + fbw];
    f32x4 pacc[2][4];
#pragma unroll
    for (int g = 0; g < 2; g++) {
      pacc[g][0] = bvp;
      pacc[g][1] = (f32x4){0.f, 0.f, 0.f, 0.f};
      pacc[g][2] = (f32x4){0.f, 0.f, 0.f, 0.f};
      pacc[g][3] = (f32x4){0.f, 0.f, 0.f, 0.f};
    }
#pragma unroll
    for (int kk = 0; kk < 34; kk++) {
      short8 af = pf[kk & 7];
      if (kk + 8 < 34) pf[kk & 7] = mrow[(kk + 8) * 64];
      int i = kk >> 1;
#pragma unroll
      for (int g = 0; g < 2; g++) {
        short8 bf = *(const short8*)(hb0 + g * 34816 +
                                     hswz(i * 16 + ln15, (kk & 1) * 64 + quad * 16));
        pacc[g][kk & 3] = mfma16(af, bf, pacc[g][kk & 3]);
      }
    }
    zcv[0] = (pacc[0][0] + pacc[0][1]) + (pacc[0][2] + pacc[0][3]);
    zcv[1] = (pacc[1][0] + pacc[1][1]) + (pacc[1][2] + pacc[1][3]);
  }
  // prefetch Wp2 fragments; latency hides behind zb pack + barrier
  short8 wp2f[4][2];
#pragma unroll
  for (int t = 0; t < 4; t++) {
    int ot = WV + 4 * t;
    wp2f[t][0] = *(const short8*)(Wp2b + (ot * 16 + ln15) * 64 + quad * 8);
    wp2f[t][1] = *(const short8*)(Wp2b + (ot * 16 + ln15) * 64 + 32 + quad * 8);
  }
#pragma unroll
  for (int g = 0; g < 2; g++) {
    char* zbB = (char*)(xs + g * 816);  // overlay: xs dead since L1
    u32x2 pk;
    pk.x = pk2(fmaxf(zcv[g].x, 0.f), fmaxf(zcv[g].y, 0.f));
    pk.y = pk2(fmaxf(zcv[g].z, 0.f), fmaxf(zcv[g].w, 0.f));
    *(u32x2*)(zbB + hswz(ln15, fbw * 2)) = pk;
  }
  __syncthreads();  // zb ready

  // ---- Pool layer 2: out = Wp2 * z + bp2, both tiles ----
#pragma unroll
  for (int g = 0; g < 2; g++) {
    char* zbB = (char*)(xs + g * 816);
    short8 bf0 = *(const short8*)(zbB + hswz(ln15, quad * 16));
    short8 bf1 = *(const short8*)(zbB + hswz(ln15, 64 + quad * 16));
    int e0g = bx * 32 + g * 16;
#pragma unroll
    for (int t = 0; t < 4; t++) {
      int ot = WV + 4 * t;
      f32x4 a = (f32x4){0.f, 0.f, 0.f, 0.f};
      a = mfma16(wp2f[t][0], bf0, a);
      a = mfma16(wp2f[t][1], bf1, a);
      int ob = ot * 16 + quad * 4;
      f32x4 bv = *(const f32x4*)&bp2g[ob];
      f32x4 res = a + bv;
      *(f32x4*)(OUT + (size_t)(e0g + ln15) * 256 + ob) = res;
    }
  }
}

// ---------------- main fused kernel ----------------
// 256 threads / 4 waves, dual 16-elem tiles per wave. Wave-specialized
// single-body template (R5): registers stay SROA'd, h2 packed to bf16
// before the WAR barrier. LDS = 69632+6528+512 -> 2 blocks/CU.
__launch_bounds__(256, 2)
__global__ void gcn_main(const float* __restrict__ X,
                         const short* __restrict__ Mb,
                         const short* __restrict__ Wp2b,
                         const short* __restrict__ W2b,
                         const short* __restrict__ W1b,
                         const float* __restrict__ bp1p,
                         const float* __restrict__ b2g,
                         const float* __restrict__ bp2g,
                         float* __restrict__ OUT) {
  __shared__ __align__(16) short hbuf[2 * 272 * 64];  // 69632 B (2 tiles)
  __shared__ __align__(16) float xs[2 * 816];         // 6528 B; zb overlays late
  __shared__ __align__(16) float sbias[128];          // b2 | bp1p

  const int tid = threadIdx.x;
  const int wave = tid >> 6;
  const int lane = tid & 63;
  const int ln15 = lane & 15;
  const int quad = lane >> 4;
  const int bx = blockIdx.x;

  // ---- init ----
  for (int q = tid; q < 408; q += 256)
    ((f32x4*)xs)[q] = ((const f32x4*)(X + (size_t)bx * 1632))[q];
  short8 w1f[4];
#pragma unroll
  for (int ft = 0; ft < 4; ft++)
    w1f[ft] = *(const short8*)(W1b + (ft * 16 + ln15) * 8);
  if (tid < 128) {
    sbias[tid] = (tid < 64) ? b2g[tid] : bp1p[tid - 64];
  }
  __syncthreads();  // xs, sbias ready

  if (wave == 0)
    waveBody<0>(Mb, Wp2b, W2b, bp2g, OUT, hbuf, xs, sbias, w1f, bx, lane, ln15, quad);
  else if (wave == 1)
    waveBody<1>(Mb, Wp2b, W2b, bp2g, OUT, hbuf, xs, sbias, w1f, bx, lane, ln15, quad);
  else if (wave == 2)
    waveBody<2>(Mb, Wp2b, W2b, bp2g, OUT, hbuf, xs, sbias, w1f, bx, lane, ln15, quad);
  else
    waveBody<3>(Mb, Wp2b, W2b, bp2g, OUT, hbuf, xs, sbias, w1f, bx, lane, ln15, quad);
}

extern "C" void kernel_launch(void* const* d_in, const int* in_sizes, int n_in,
                              void* d_out, int out_size, void* d_ws, size_t ws_size,
                              hipStream_t stream) {
  const float* X = (const float*)d_in[0];
  const float* W1 = (const float*)d_in[2];
  const float* b1 = (const float*)d_in[3];
  const float* W2 = (const float*)d_in[4];
  const float* b2 = (const float*)d_in[5];
  const float* W3 = (const float*)d_in[6];
  const float* b3 = (const float*)d_in[7];
  const float* Wp1 = (const float*)d_in[8];
  const float* bp1 = (const float*)d_in[9];
  const float* Wp2 = (const float*)d_in[10];
  const float* bp2 = (const float*)d_in[11];
  float* OUT = (float*)d_out;
  const int B = in_sizes[0] / 51;

  char* ws = (char*)d_ws;
  short* Mb = (short*)(ws + 0);          // 64*1088*2 = 139264 (swizzled)
  short* Wp2b = (short*)(ws + 139264);   // 32768
  short* W2b = (short*)(ws + 172032);    // 8192
  short* W1b = (short*)(ws + 180224);    // 1024 (k=3 slot = b1)
  float* bp1p = (float*)(ws + 181248);   // 256

  prep<<<370, 256, 0, stream>>>(W1, W2, Wp2, W3, Wp1, b3, bp1, b1,
                                W1b, W2b, Wp2b, Mb, bp1p);
  gcn_main<<<B / 32, 256, 0, stream>>>(X, Mb, Wp2b, W2b, W1b, bp1p,
                                       b2, bp2, OUT);
}